// Round 1
// baseline (133.048 us; speedup 1.0000x reference)
//
#include <hip/hip_runtime.h>
#include <math.h>

#define N_ROWS 512
#define M_LEN  4096
#define D_DIM  8

__device__ __forceinline__ float2 f2(float x, float y) { return make_float2(x, y); }

static constexpr float TWO_PI = 6.283185307179586476925f;

// ---------------------------------------------------------------------------
// Softmaxes: blocks 0..7 -> softmax of C_tilde[d, :] over N=512
//            blocks 8..9 -> softmax of S_tilde[n, :] over d=8 (thread per n)
// ---------------------------------------------------------------------------
__global__ __launch_bounds__(256) void softmax_kernel(
    const float* __restrict__ Ct, const float* __restrict__ St,
    float* __restrict__ C, float* __restrict__ S) {
  int b = blockIdx.x, tid = threadIdx.x;
  if (b < D_DIM) {
    __shared__ float red[256];
    const float* row = Ct + b * N_ROWS;
    float v0 = row[tid], v1 = row[tid + 256];
    float mx = fmaxf(v0, v1);
    red[tid] = mx; __syncthreads();
    for (int s = 128; s > 0; s >>= 1) {
      if (tid < s) red[tid] = fmaxf(red[tid], red[tid + s]);
      __syncthreads();
    }
    float m = red[0];
    __syncthreads();
    float e0 = __expf(v0 - m), e1 = __expf(v1 - m);
    red[tid] = e0 + e1; __syncthreads();
    for (int s = 128; s > 0; s >>= 1) {
      if (tid < s) red[tid] += red[tid + s];
      __syncthreads();
    }
    float inv = 1.0f / red[0];
    C[b * N_ROWS + tid]       = e0 * inv;
    C[b * N_ROWS + tid + 256] = e1 * inv;
  } else {
    int n = (b - D_DIM) * 256 + tid;
    if (n < N_ROWS) {
      float v[D_DIM];
      float mx = -3.0e38f;
      #pragma unroll
      for (int d = 0; d < D_DIM; ++d) { v[d] = St[n * D_DIM + d]; mx = fmaxf(mx, v[d]); }
      float sum = 0.f;
      #pragma unroll
      for (int d = 0; d < D_DIM; ++d) { v[d] = __expf(v[d] - mx); sum += v[d]; }
      float inv = 1.0f / sum;
      #pragma unroll
      for (int d = 0; d < D_DIM; ++d) S[n * D_DIM + d] = v[d] * inv;
    }
  }
}

// ---------------------------------------------------------------------------
// Radix-2 DIT FFT, 4096 points, one block (256 threads) per row. LDS 32 KB.
// X real in, X_F complex out. Matches numpy fft convention:
//   X_F[k] = sum_j x[j] exp(-2*pi*i*j*k/M)
// ---------------------------------------------------------------------------
__global__ __launch_bounds__(256) void fft_kernel(
    const float* __restrict__ X, float2* __restrict__ XF) {
  __shared__ float2 buf[M_LEN];
  int row = blockIdx.x;
  int tid = threadIdx.x;
  const float* x = X + (size_t)row * M_LEN;
  for (int j = tid; j < M_LEN; j += 256) {
    int r = (int)(__brev((unsigned)j) >> 20);   // 12-bit reversal
    buf[r] = f2(x[j], 0.0f);
  }
  __syncthreads();
  for (int s = 1; s <= 12; ++s) {
    int half = 1 << (s - 1);
    int mlen = 1 << s;
    float base = -TWO_PI / (float)mlen;
    for (int t = tid; t < (M_LEN >> 1); t += 256) {
      int k   = t & (half - 1);
      int grp = t >> (s - 1);
      int i0  = grp * mlen + k;
      int i1  = i0 + half;
      float sw, cw;
      __sincosf(base * (float)k, &sw, &cw);
      float2 a = buf[i0], b = buf[i1];
      float2 wb = f2(cw * b.x - sw * b.y, cw * b.y + sw * b.x);
      buf[i0] = f2(a.x + wb.x, a.y + wb.y);
      buf[i1] = f2(a.x - wb.x, a.y - wb.y);
    }
    __syncthreads();
  }
  for (int j = tid; j < M_LEN; j += 256)
    XF[(size_t)row * M_LEN + j] = buf[j];
}

// ---------------------------------------------------------------------------
// A_F[d,m] = sum_n C[d,n] * X_F[n,m] * exp(+2*pi*i * tau[n,d] * m / M)
// one thread per (d,m); 8*4096 threads, n-loop of 512.
// ---------------------------------------------------------------------------
__global__ __launch_bounds__(256) void af_kernel(
    const float2* __restrict__ XF, const float* __restrict__ C,
    const float* __restrict__ tau, float2* __restrict__ AF) {
  int idx = blockIdx.x * 256 + threadIdx.x;    // over d*M
  int d = idx >> 12;
  int m = idx & (M_LEN - 1);
  float fm = (float)m * (1.0f / (float)M_LEN);
  float accr = 0.f, acci = 0.f;
  #pragma unroll 8
  for (int n = 0; n < N_ROWS; ++n) {
    float c = C[d * N_ROWS + n];
    float t = tau[n * D_DIM + d];
    float sa, ca;
    __sincosf(TWO_PI * t * fm, &sa, &ca);
    float2 Xv = XF[(size_t)n * M_LEN + m];
    // conj(omega) = (ca, +sa)
    accr += c * (Xv.x * ca - Xv.y * sa);
    acci += c * (Xv.x * sa + Xv.y * ca);
  }
  AF[idx] = f2(accr, acci);
}

// ---------------------------------------------------------------------------
// x[n,m] = sum_d S[n,d] * exp(-2*pi*i*tau[n,d]*m/M) * A_F[d,m]
// one thread per (n,m). Interleaved complex store (float2).
// ---------------------------------------------------------------------------
__global__ __launch_bounds__(256) void out_kernel(
    const float2* __restrict__ AF, const float* __restrict__ S,
    const float* __restrict__ tau, float* __restrict__ out, int interleaved) {
  int idx = blockIdx.x * 256 + threadIdx.x;   // over N*M
  int n = idx >> 12;
  int m = idx & (M_LEN - 1);
  float fm = (float)m * (1.0f / (float)M_LEN);
  float xr = 0.f, xi = 0.f;
  #pragma unroll
  for (int d = 0; d < D_DIM; ++d) {
    float s = S[n * D_DIM + d];
    float t = tau[n * D_DIM + d];
    float sa, ca;
    __sincosf(TWO_PI * t * fm, &sa, &ca);
    float2 A = AF[(d << 12) + m];
    // omega = (ca, -sa); omega*A = (ca*Ar + sa*Ai, ca*Ai - sa*Ar)
    xr += s * (ca * A.x + sa * A.y);
    xi += s * (ca * A.y - sa * A.x);
  }
  if (interleaved) {
    ((float2*)out)[idx] = f2(xr, xi);
  } else {
    out[idx] = xr;   // fallback if harness expects real-only
  }
}

extern "C" void kernel_launch(void* const* d_in, const int* in_sizes, int n_in,
                              void* d_out, int out_size, void* d_ws, size_t ws_size,
                              hipStream_t stream) {
  const float* X  = (const float*)d_in[0];   // [512, 4096]
  const float* Ct = (const float*)d_in[1];   // [8, 512]
  const float* St = (const float*)d_in[2];   // [512, 8]
  const float* tau= (const float*)d_in[3];   // [512, 8]

  char* ws = (char*)d_ws;
  const size_t XF_BYTES = (size_t)N_ROWS * M_LEN * sizeof(float2);   // 16 MB
  const size_t AF_BYTES = (size_t)D_DIM * M_LEN * sizeof(float2);    // 256 KB
  const size_t C_BYTES  = (size_t)D_DIM * N_ROWS * sizeof(float);    // 16 KB
  float2* XF = (float2*)ws;
  float2* AF = (float2*)(ws + XF_BYTES);
  float*  C  = (float*)(ws + XF_BYTES + AF_BYTES);
  float*  S  = (float*)(ws + XF_BYTES + AF_BYTES + C_BYTES);

  int interleaved = (out_size >= 2 * N_ROWS * M_LEN) ? 1 : 0;

  softmax_kernel<<<D_DIM + (N_ROWS + 255) / 256, 256, 0, stream>>>(Ct, St, C, S);
  fft_kernel<<<N_ROWS, 256, 0, stream>>>(X, XF);
  af_kernel<<<(D_DIM * M_LEN) / 256, 256, 0, stream>>>(XF, C, tau, AF);
  out_kernel<<<(N_ROWS * M_LEN) / 256, 256, 0, stream>>>(AF, S, tau, (float*)d_out, interleaved);
}

// Round 5
// 131.000 us; speedup vs baseline: 1.0156x; 1.0156x over previous
//
#include <hip/hip_runtime.h>
#include <math.h>

#define N_ROWS 512
#define M_LEN  4096
#define D_DIM  8

__device__ __forceinline__ float2 f2(float x, float y) { return make_float2(x, y); }

static constexpr float TWO_PI = 6.283185307179586476925f;

// ---------------------------------------------------------------------------
// Softmaxes: blocks 0..7 -> softmax of C_tilde[d, :] over N=512
//            blocks 8..9 -> softmax of S_tilde[n, :] over d=8 (thread per n)
// ---------------------------------------------------------------------------
__global__ __launch_bounds__(256) void softmax_kernel(
    const float* __restrict__ Ct, const float* __restrict__ St,
    float* __restrict__ C, float* __restrict__ S) {
  int b = blockIdx.x, tid = threadIdx.x;
  if (b < D_DIM) {
    __shared__ float red[256];
    const float* row = Ct + b * N_ROWS;
    float v0 = row[tid], v1 = row[tid + 256];
    float mx = fmaxf(v0, v1);
    red[tid] = mx; __syncthreads();
    for (int s = 128; s > 0; s >>= 1) {
      if (tid < s) red[tid] = fmaxf(red[tid], red[tid + s]);
      __syncthreads();
    }
    float m = red[0];
    __syncthreads();
    float e0 = __expf(v0 - m), e1 = __expf(v1 - m);
    red[tid] = e0 + e1; __syncthreads();
    for (int s = 128; s > 0; s >>= 1) {
      if (tid < s) red[tid] += red[tid + s];
      __syncthreads();
    }
    float inv = 1.0f / red[0];
    C[b * N_ROWS + tid]       = e0 * inv;
    C[b * N_ROWS + tid + 256] = e1 * inv;
  } else {
    int n = (b - D_DIM) * 256 + tid;
    if (n < N_ROWS) {
      float v[D_DIM];
      float mx = -3.0e38f;
      #pragma unroll
      for (int d = 0; d < D_DIM; ++d) { v[d] = St[n * D_DIM + d]; mx = fmaxf(mx, v[d]); }
      float sum = 0.f;
      #pragma unroll
      for (int d = 0; d < D_DIM; ++d) { v[d] = __expf(v[d] - mx); sum += v[d]; }
      float inv = 1.0f / sum;
      #pragma unroll
      for (int d = 0; d < D_DIM; ++d) S[n * D_DIM + d] = v[d] * inv;
    }
  }
}

// ---------------------------------------------------------------------------
// Radix-2 DIT FFT, 4096 points, one block (256 threads) per row. LDS 32 KB.
// X real in, X_F complex out. Matches numpy fft convention:
//   X_F[k] = sum_j x[j] exp(-2*pi*i*j*k/M)
// ---------------------------------------------------------------------------
__global__ __launch_bounds__(256) void fft_kernel(
    const float* __restrict__ X, float2* __restrict__ XF) {
  __shared__ float2 buf[M_LEN];
  int row = blockIdx.x;
  int tid = threadIdx.x;
  const float* x = X + (size_t)row * M_LEN;
  for (int j = tid; j < M_LEN; j += 256) {
    int r = (int)(__brev((unsigned)j) >> 20);   // 12-bit reversal
    buf[r] = f2(x[j], 0.0f);
  }
  __syncthreads();
  for (int s = 1; s <= 12; ++s) {
    int half = 1 << (s - 1);
    int mlen = 1 << s;
    float base = -TWO_PI / (float)mlen;
    for (int t = tid; t < (M_LEN >> 1); t += 256) {
      int k   = t & (half - 1);
      int grp = t >> (s - 1);
      int i0  = grp * mlen + k;
      int i1  = i0 + half;
      float sw, cw;
      __sincosf(base * (float)k, &sw, &cw);
      float2 a = buf[i0], b = buf[i1];
      float2 wb = f2(cw * b.x - sw * b.y, cw * b.y + sw * b.x);
      buf[i0] = f2(a.x + wb.x, a.y + wb.y);
      buf[i1] = f2(a.x - wb.x, a.y - wb.y);
    }
    __syncthreads();
  }
  for (int j = tid; j < M_LEN; j += 256)
    XF[(size_t)row * M_LEN + j] = buf[j];
}

// ---------------------------------------------------------------------------
// A_F[d,m] = sum_n C[d,n] * X_F[n,m] * exp(+2*pi*i * tau[n,d] * m / M)
// one thread per (d,m); 8*4096 threads, n-loop of 512.
// ---------------------------------------------------------------------------
__global__ __launch_bounds__(256) void af_kernel(
    const float2* __restrict__ XF, const float* __restrict__ C,
    const float* __restrict__ tau, float2* __restrict__ AF) {
  int idx = blockIdx.x * 256 + threadIdx.x;    // over d*M
  int d = idx >> 12;
  int m = idx & (M_LEN - 1);
  float fm = (float)m * (1.0f / (float)M_LEN);
  float accr = 0.f, acci = 0.f;
  #pragma unroll 8
  for (int n = 0; n < N_ROWS; ++n) {
    float c = C[d * N_ROWS + n];
    float t = tau[n * D_DIM + d];
    float sa, ca;
    __sincosf(TWO_PI * t * fm, &sa, &ca);
    float2 Xv = XF[(size_t)n * M_LEN + m];
    // conj(omega) = (ca, +sa)
    accr += c * (Xv.x * ca - Xv.y * sa);
    acci += c * (Xv.x * sa + Xv.y * ca);
  }
  AF[idx] = f2(accr, acci);
}

// ---------------------------------------------------------------------------
// x[n,m] = sum_d S[n,d] * exp(-2*pi*i*tau[n,d]*m/M) * A_F[d,m]
// one thread per (n,m). Interleaved complex store (float2).
// ---------------------------------------------------------------------------
__global__ __launch_bounds__(256) void out_kernel(
    const float2* __restrict__ AF, const float* __restrict__ S,
    const float* __restrict__ tau, float* __restrict__ out, int interleaved) {
  int idx = blockIdx.x * 256 + threadIdx.x;   // over N*M
  int n = idx >> 12;
  int m = idx & (M_LEN - 1);
  float fm = (float)m * (1.0f / (float)M_LEN);
  float xr = 0.f, xi = 0.f;
  #pragma unroll
  for (int d = 0; d < D_DIM; ++d) {
    float s = S[n * D_DIM + d];
    float t = tau[n * D_DIM + d];
    float sa, ca;
    __sincosf(TWO_PI * t * fm, &sa, &ca);
    float2 A = AF[(d << 12) + m];
    // omega = (ca, -sa); omega*A = (ca*Ar + sa*Ai, ca*Ai - sa*Ar)
    xr += s * (ca * A.x + sa * A.y);
    xi += s * (ca * A.y - sa * A.x);
  }
  if (interleaved) {
    ((float2*)out)[idx] = f2(xr, xi);
  } else {
    out[idx] = xr;   // fallback if harness expects real-only
  }
}

extern "C" void kernel_launch(void* const* d_in, const int* in_sizes, int n_in,
                              void* d_out, int out_size, void* d_ws, size_t ws_size,
                              hipStream_t stream) {
  const float* X  = (const float*)d_in[0];   // [512, 4096]
  const float* Ct = (const float*)d_in[1];   // [8, 512]
  const float* St = (const float*)d_in[2];   // [512, 8]
  const float* tau= (const float*)d_in[3];   // [512, 8]

  char* ws = (char*)d_ws;
  const size_t XF_BYTES = (size_t)N_ROWS * M_LEN * sizeof(float2);   // 16 MB
  const size_t AF_BYTES = (size_t)D_DIM * M_LEN * sizeof(float2);    // 256 KB
  const size_t C_BYTES  = (size_t)D_DIM * N_ROWS * sizeof(float);    // 16 KB
  float2* XF = (float2*)ws;
  float2* AF = (float2*)(ws + XF_BYTES);
  float*  C  = (float*)(ws + XF_BYTES + AF_BYTES);
  float*  S  = (float*)(ws + XF_BYTES + AF_BYTES + C_BYTES);

  int interleaved = (out_size >= 2 * N_ROWS * M_LEN) ? 1 : 0;

  softmax_kernel<<<D_DIM + (N_ROWS + 255) / 256, 256, 0, stream>>>(Ct, St, C, S);
  fft_kernel<<<N_ROWS, 256, 0, stream>>>(X, XF);
  af_kernel<<<(D_DIM * M_LEN) / 256, 256, 0, stream>>>(XF, C, tau, AF);
  out_kernel<<<(N_ROWS * M_LEN) / 256, 256, 0, stream>>>(AF, S, tau, (float*)d_out, interleaved);
}

// Round 6
// 117.068 us; speedup vs baseline: 1.1365x; 1.1190x over previous
//
#include <hip/hip_runtime.h>
#include <math.h>

#define N_ROWS 512
#define M_LEN  4096
#define D_DIM  8
#define NCHUNK 8

__device__ __forceinline__ float2 f2(float x, float y) { return make_float2(x, y); }

static constexpr float TWO_PI = 6.283185307179586476925f;

// ---------------------------------------------------------------------------
// Softmaxes (round-1 verbatim, proven): blocks 0..7 -> softmax C_tilde[d,:]
// over N; blocks 8..9 -> softmax S_tilde[n,:] over d.
// ---------------------------------------------------------------------------
__global__ __launch_bounds__(256) void softmax_kernel(
    const float* __restrict__ Ct, const float* __restrict__ St,
    float* __restrict__ C, float* __restrict__ S) {
  int b = blockIdx.x, tid = threadIdx.x;
  if (b < D_DIM) {
    __shared__ float red[256];
    const float* row = Ct + b * N_ROWS;
    float v0 = row[tid], v1 = row[tid + 256];
    float mx = fmaxf(v0, v1);
    red[tid] = mx; __syncthreads();
    for (int s = 128; s > 0; s >>= 1) {
      if (tid < s) red[tid] = fmaxf(red[tid], red[tid + s]);
      __syncthreads();
    }
    float m = red[0];
    __syncthreads();
    float e0 = __expf(v0 - m), e1 = __expf(v1 - m);
    red[tid] = e0 + e1; __syncthreads();
    for (int s = 128; s > 0; s >>= 1) {
      if (tid < s) red[tid] += red[tid + s];
      __syncthreads();
    }
    float inv = 1.0f / red[0];
    C[b * N_ROWS + tid]       = e0 * inv;
    C[b * N_ROWS + tid + 256] = e1 * inv;
  } else {
    int n = (b - D_DIM) * 256 + tid;
    if (n < N_ROWS) {
      float v[D_DIM];
      float mx = -3.0e38f;
      #pragma unroll
      for (int d = 0; d < D_DIM; ++d) { v[d] = St[n * D_DIM + d]; mx = fmaxf(mx, v[d]); }
      float sum = 0.f;
      #pragma unroll
      for (int d = 0; d < D_DIM; ++d) { v[d] = __expf(v[d] - mx); sum += v[d]; }
      float inv = 1.0f / sum;
      #pragma unroll
      for (int d = 0; d < D_DIM; ++d) S[n * D_DIM + d] = v[d] * inv;
    }
  }
}

// ---------------------------------------------------------------------------
// Radix-2 DIT FFT (round-1 verbatim, proven). One block per row, LDS 32 KB.
// ---------------------------------------------------------------------------
__global__ __launch_bounds__(256) void fft_kernel(
    const float* __restrict__ X, float2* __restrict__ XF) {
  __shared__ float2 buf[M_LEN];
  int row = blockIdx.x;
  int tid = threadIdx.x;
  const float* x = X + (size_t)row * M_LEN;
  for (int j = tid; j < M_LEN; j += 256) {
    int r = (int)(__brev((unsigned)j) >> 20);   // 12-bit reversal
    buf[r] = f2(x[j], 0.0f);
  }
  __syncthreads();
  for (int s = 1; s <= 12; ++s) {
    int half = 1 << (s - 1);
    int mlen = 1 << s;
    float base = -TWO_PI / (float)mlen;
    for (int t = tid; t < (M_LEN >> 1); t += 256) {
      int k   = t & (half - 1);
      int grp = t >> (s - 1);
      int i0  = grp * mlen + k;
      int i1  = i0 + half;
      float sw, cw;
      __sincosf(base * (float)k, &sw, &cw);
      float2 a = buf[i0], b = buf[i1];
      float2 wb = f2(cw * b.x - sw * b.y, cw * b.y + sw * b.x);
      buf[i0] = f2(a.x + wb.x, a.y + wb.y);
      buf[i1] = f2(a.x - wb.x, a.y - wb.y);
    }
    __syncthreads();
  }
  for (int j = tid; j < M_LEN; j += 256)
    XF[(size_t)row * M_LEN + j] = buf[j];
}

// ---------------------------------------------------------------------------
// zero AF (ws is poisoned to 0xAA before every launch)
// ---------------------------------------------------------------------------
__global__ __launch_bounds__(256) void zero_af_kernel(float4* __restrict__ AF) {
  int i = blockIdx.x * 256 + threadIdx.x;          // 16384 float4 = 256 KB
  if (i < (D_DIM * M_LEN) / 2)
    AF[i] = make_float4(0.f, 0.f, 0.f, 0.f);
}

// ---------------------------------------------------------------------------
// af (NEW, chunked): same thread mapping as round-1 (idx over d*M), but the
// n-loop is split 8x across blocks; partials accumulated into AF[d][m] via
// atomicAdd. grid = NCHUNK * 128 blocks -> 16 waves/CU for latency hiding.
// ---------------------------------------------------------------------------
__global__ __launch_bounds__(256) void af_kernel(
    const float2* __restrict__ XF, const float* __restrict__ C,
    const float* __restrict__ tau, float* __restrict__ AF) {
  int bid   = blockIdx.x;
  int chunk = bid >> 7;                            // 0..NCHUNK-1
  int idx   = (bid & 127) * 256 + threadIdx.x;     // 0..32767 over d*M
  int d = idx >> 12;
  int m = idx & (M_LEN - 1);
  float fm = (float)m * (1.0f / (float)M_LEN);
  float accr = 0.f, acci = 0.f;
  int n0 = chunk * (N_ROWS / NCHUNK);
  #pragma unroll 8
  for (int nn = 0; nn < N_ROWS / NCHUNK; ++nn) {
    int n = n0 + nn;
    float c = C[d * N_ROWS + n];
    float t = tau[n * D_DIM + d];
    float sa, ca;
    __sincosf(TWO_PI * t * fm, &sa, &ca);
    float2 Xv = XF[(size_t)n * M_LEN + m];
    // conj(omega) = (ca, +sa)
    accr += c * (Xv.x * ca - Xv.y * sa);
    acci += c * (Xv.x * sa + Xv.y * ca);
  }
  if (idx < D_DIM * M_LEN) {
    atomicAdd(&AF[2 * idx],     accr);
    atomicAdd(&AF[2 * idx + 1], acci);
  }
}

// ---------------------------------------------------------------------------
// out (round-1 verbatim, proven): x[n,m] = sum_d S[n,d]*omega*AF[d,m]
// ---------------------------------------------------------------------------
__global__ __launch_bounds__(256) void out_kernel(
    const float2* __restrict__ AF, const float* __restrict__ S,
    const float* __restrict__ tau, float* __restrict__ out, int interleaved) {
  int idx = blockIdx.x * 256 + threadIdx.x;   // over N*M
  int n = idx >> 12;
  int m = idx & (M_LEN - 1);
  float fm = (float)m * (1.0f / (float)M_LEN);
  float xr = 0.f, xi = 0.f;
  #pragma unroll
  for (int d = 0; d < D_DIM; ++d) {
    float s = S[n * D_DIM + d];
    float t = tau[n * D_DIM + d];
    float sa, ca;
    __sincosf(TWO_PI * t * fm, &sa, &ca);
    float2 A = AF[(d << 12) + m];
    // omega = (ca, -sa); omega*A = (ca*Ar + sa*Ai, ca*Ai - sa*Ar)
    xr += s * (ca * A.x + sa * A.y);
    xi += s * (ca * A.y - sa * A.x);
  }
  if (interleaved) {
    ((float2*)out)[idx] = f2(xr, xi);
  } else {
    out[idx] = xr;
  }
}

extern "C" void kernel_launch(void* const* d_in, const int* in_sizes, int n_in,
                              void* d_out, int out_size, void* d_ws, size_t ws_size,
                              hipStream_t stream) {
  const float* X  = (const float*)d_in[0];   // [512, 4096]
  const float* Ct = (const float*)d_in[1];   // [8, 512]
  const float* St = (const float*)d_in[2];   // [512, 8]
  const float* tau= (const float*)d_in[3];   // [512, 8]

  // workspace layout byte-identical to round-1 (passed twice)
  char* ws = (char*)d_ws;
  const size_t XF_BYTES = (size_t)N_ROWS * M_LEN * sizeof(float2);   // 16 MB
  const size_t AF_BYTES = (size_t)D_DIM * M_LEN * sizeof(float2);    // 256 KB
  const size_t C_BYTES  = (size_t)D_DIM * N_ROWS * sizeof(float);    // 16 KB
  float2* XF = (float2*)ws;
  float2* AF = (float2*)(ws + XF_BYTES);
  float*  C  = (float*)(ws + XF_BYTES + AF_BYTES);
  float*  S  = (float*)(ws + XF_BYTES + AF_BYTES + C_BYTES);

  int interleaved = (out_size >= 2 * N_ROWS * M_LEN) ? 1 : 0;

  softmax_kernel<<<D_DIM + (N_ROWS + 255) / 256, 256, 0, stream>>>(Ct, St, C, S);
  fft_kernel<<<N_ROWS, 256, 0, stream>>>(X, XF);
  zero_af_kernel<<<(D_DIM * M_LEN / 2 + 255) / 256, 256, 0, stream>>>((float4*)AF);
  af_kernel<<<NCHUNK * 128, 256, 0, stream>>>(XF, C, tau, (float*)AF);
  out_kernel<<<(N_ROWS * M_LEN) / 256, 256, 0, stream>>>(AF, S, tau, (float*)d_out, interleaved);
}

// Round 7
// 115.157 us; speedup vs baseline: 1.1554x; 1.0166x over previous
//
#include <hip/hip_runtime.h>
#include <math.h>

#define N_ROWS 512
#define M_LEN  4096
#define D_DIM  8
#define NCHUNK 8

__device__ __forceinline__ float2 f2(float x, float y) { return make_float2(x, y); }
__device__ __forceinline__ float2 cmul(float2 a, float2 b){
  return f2(a.x*b.x - a.y*b.y, a.x*b.y + a.y*b.x);
}
__device__ __forceinline__ float2 cadd(float2 a, float2 b){ return f2(a.x+b.x, a.y+b.y); }
__device__ __forceinline__ float2 csub(float2 a, float2 b){ return f2(a.x-b.x, a.y-b.y); }
// LDS anti-conflict padding: strictly increasing -> injective; ph(4095)=4365
__device__ __forceinline__ int ph(int i){ return i + (i>>4) + (i>>8); }
// base-4 digit reversal of 6 digits (involution on [0,4096))
__device__ __forceinline__ int dr6(int j){
  int r = 0;
  #pragma unroll
  for (int i = 0; i < 6; ++i){ r = (r<<2) | (j & 3); j >>= 2; }
  return r;
}

static constexpr float TWO_PI = 6.283185307179586476925f;

// ---------------------------------------------------------------------------
// Softmaxes (round-1 verbatim, proven)
// ---------------------------------------------------------------------------
__global__ __launch_bounds__(256) void softmax_kernel(
    const float* __restrict__ Ct, const float* __restrict__ St,
    float* __restrict__ C, float* __restrict__ S) {
  int b = blockIdx.x, tid = threadIdx.x;
  if (b < D_DIM) {
    __shared__ float red[256];
    const float* row = Ct + b * N_ROWS;
    float v0 = row[tid], v1 = row[tid + 256];
    float mx = fmaxf(v0, v1);
    red[tid] = mx; __syncthreads();
    for (int s = 128; s > 0; s >>= 1) {
      if (tid < s) red[tid] = fmaxf(red[tid], red[tid + s]);
      __syncthreads();
    }
    float m = red[0];
    __syncthreads();
    float e0 = __expf(v0 - m), e1 = __expf(v1 - m);
    red[tid] = e0 + e1; __syncthreads();
    for (int s = 128; s > 0; s >>= 1) {
      if (tid < s) red[tid] += red[tid + s];
      __syncthreads();
    }
    float inv = 1.0f / red[0];
    C[b * N_ROWS + tid]       = e0 * inv;
    C[b * N_ROWS + tid + 256] = e1 * inv;
  } else {
    int n = (b - D_DIM) * 256 + tid;
    if (n < N_ROWS) {
      float v[D_DIM];
      float mx = -3.0e38f;
      #pragma unroll
      for (int d = 0; d < D_DIM; ++d) { v[d] = St[n * D_DIM + d]; mx = fmaxf(mx, v[d]); }
      float sum = 0.f;
      #pragma unroll
      for (int d = 0; d < D_DIM; ++d) { v[d] = __expf(v[d] - mx); sum += v[d]; }
      float inv = 1.0f / sum;
      #pragma unroll
      for (int d = 0; d < D_DIM; ++d) S[n * D_DIM + d] = v[d] * inv;
    }
  }
}

// ---------------------------------------------------------------------------
// Radix-4 DIT FFT (THE one new concept this round). 6 stages, ph-padded LDS.
//   X_F[k] = sum_j x[j] exp(-2*pi*i*j*k/M)
// ---------------------------------------------------------------------------
__global__ __launch_bounds__(256) void fft_kernel(
    const float* __restrict__ X, float2* __restrict__ XF) {
  __shared__ float2 buf[4368];             // ph(4095)=4365, 34.9 KB
  int row = blockIdx.x;
  int tid = threadIdx.x;
  const float* x = X + (size_t)row * M_LEN;
  // digit-reversed load (dr6 is an involution): buf[r] = x[dr6(r)]
  for (int j = tid; j < M_LEN; j += 256)
    buf[ph(dr6(j))] = f2(x[j], 0.0f);
  __syncthreads();
  for (int s = 0; s < 6; ++s) {
    int quarter = 1 << (2*s);
    float angf = -TWO_PI / (float)(quarter << 2);
    for (int bi = tid; bi < 1024; bi += 256) {
      int k  = bi & (quarter - 1);
      int g  = bi >> (2*s);
      int i0 = (g << (2*s + 2)) + k;
      float sw, cw; __sincosf(angf * (float)k, &sw, &cw);
      float2 w1 = f2(cw, sw);
      float2 w2 = cmul(w1, w1);
      float2 w3 = cmul(w2, w1);
      float2 a0 = buf[ph(i0)];
      float2 a1 = cmul(buf[ph(i0 +   quarter)], w1);
      float2 a2 = cmul(buf[ph(i0 + 2*quarter)], w2);
      float2 a3 = cmul(buf[ph(i0 + 3*quarter)], w3);
      float2 t0 = cadd(a0, a2), t1 = csub(a0, a2);
      float2 t2 = cadd(a1, a3), t3 = csub(a1, a3);
      buf[ph(i0)]             = cadd(t0, t2);            // y0
      buf[ph(i0 +   quarter)] = f2(t1.x + t3.y, t1.y - t3.x);  // y1 = t1 - i*t3
      buf[ph(i0 + 2*quarter)] = csub(t0, t2);            // y2
      buf[ph(i0 + 3*quarter)] = f2(t1.x - t3.y, t1.y + t3.x);  // y3 = t1 + i*t3
    }
    __syncthreads();
  }
  for (int j = tid; j < M_LEN; j += 256)
    XF[(size_t)row * M_LEN + j] = buf[ph(j)];
}

// ---------------------------------------------------------------------------
// zero AF (ws is poisoned to 0xAA before every launch)
// ---------------------------------------------------------------------------
__global__ __launch_bounds__(256) void zero_af_kernel(float4* __restrict__ AF) {
  int i = blockIdx.x * 256 + threadIdx.x;          // 16384 float4 = 256 KB
  if (i < (D_DIM * M_LEN) / 2)
    AF[i] = make_float4(0.f, 0.f, 0.f, 0.f);
}

// ---------------------------------------------------------------------------
// af (round-6 verbatim, proven): chunked, atomicAdd into AF[d][m]
// ---------------------------------------------------------------------------
__global__ __launch_bounds__(256) void af_kernel(
    const float2* __restrict__ XF, const float* __restrict__ C,
    const float* __restrict__ tau, float* __restrict__ AF) {
  int bid   = blockIdx.x;
  int chunk = bid >> 7;                            // 0..NCHUNK-1
  int idx   = (bid & 127) * 256 + threadIdx.x;     // 0..32767 over d*M
  int d = idx >> 12;
  int m = idx & (M_LEN - 1);
  float fm = (float)m * (1.0f / (float)M_LEN);
  float accr = 0.f, acci = 0.f;
  int n0 = chunk * (N_ROWS / NCHUNK);
  #pragma unroll 8
  for (int nn = 0; nn < N_ROWS / NCHUNK; ++nn) {
    int n = n0 + nn;
    float c = C[d * N_ROWS + n];
    float t = tau[n * D_DIM + d];
    float sa, ca;
    __sincosf(TWO_PI * t * fm, &sa, &ca);
    float2 Xv = XF[(size_t)n * M_LEN + m];
    // conj(omega) = (ca, +sa)
    accr += c * (Xv.x * ca - Xv.y * sa);
    acci += c * (Xv.x * sa + Xv.y * ca);
  }
  if (idx < D_DIM * M_LEN) {
    atomicAdd(&AF[2 * idx],     accr);
    atomicAdd(&AF[2 * idx + 1], acci);
  }
}

// ---------------------------------------------------------------------------
// out (round-1 verbatim, proven)
// ---------------------------------------------------------------------------
__global__ __launch_bounds__(256) void out_kernel(
    const float2* __restrict__ AF, const float* __restrict__ S,
    const float* __restrict__ tau, float* __restrict__ out, int interleaved) {
  int idx = blockIdx.x * 256 + threadIdx.x;   // over N*M
  int n = idx >> 12;
  int m = idx & (M_LEN - 1);
  float fm = (float)m * (1.0f / (float)M_LEN);
  float xr = 0.f, xi = 0.f;
  #pragma unroll
  for (int d = 0; d < D_DIM; ++d) {
    float s = S[n * D_DIM + d];
    float t = tau[n * D_DIM + d];
    float sa, ca;
    __sincosf(TWO_PI * t * fm, &sa, &ca);
    float2 A = AF[(d << 12) + m];
    // omega = (ca, -sa); omega*A = (ca*Ar + sa*Ai, ca*Ai - sa*Ar)
    xr += s * (ca * A.x + sa * A.y);
    xi += s * (ca * A.y - sa * A.x);
  }
  if (interleaved) {
    ((float2*)out)[idx] = f2(xr, xi);
  } else {
    out[idx] = xr;
  }
}

extern "C" void kernel_launch(void* const* d_in, const int* in_sizes, int n_in,
                              void* d_out, int out_size, void* d_ws, size_t ws_size,
                              hipStream_t stream) {
  const float* X  = (const float*)d_in[0];   // [512, 4096]
  const float* Ct = (const float*)d_in[1];   // [8, 512]
  const float* St = (const float*)d_in[2];   // [512, 8]
  const float* tau= (const float*)d_in[3];   // [512, 8]

  // workspace layout identical to rounds 1/5/6 (passed 3x)
  char* ws = (char*)d_ws;
  const size_t XF_BYTES = (size_t)N_ROWS * M_LEN * sizeof(float2);   // 16 MB
  const size_t AF_BYTES = (size_t)D_DIM * M_LEN * sizeof(float2);    // 256 KB
  const size_t C_BYTES  = (size_t)D_DIM * N_ROWS * sizeof(float);    // 16 KB
  float2* XF = (float2*)ws;
  float2* AF = (float2*)(ws + XF_BYTES);
  float*  C  = (float*)(ws + XF_BYTES + AF_BYTES);
  float*  S  = (float*)(ws + XF_BYTES + AF_BYTES + C_BYTES);

  int interleaved = (out_size >= 2 * N_ROWS * M_LEN) ? 1 : 0;

  softmax_kernel<<<D_DIM + (N_ROWS + 255) / 256, 256, 0, stream>>>(Ct, St, C, S);
  fft_kernel<<<N_ROWS, 256, 0, stream>>>(X, XF);
  zero_af_kernel<<<(D_DIM * M_LEN / 2 + 255) / 256, 256, 0, stream>>>((float4*)AF);
  af_kernel<<<NCHUNK * 128, 256, 0, stream>>>(XF, C, tau, (float*)AF);
  out_kernel<<<(N_ROWS * M_LEN) / 256, 256, 0, stream>>>(AF, S, tau, (float*)d_out, interleaved);
}